// Round 12
// baseline (325.054 us; speedup 1.0000x reference)
//
#include <hip/hip_runtime.h>
#include <hip/hip_bf16.h>

// GraphSAGE forward: N=50000 nodes, E=600000 edges, D=H=128, G=128 graphs.
// R8:  bf16 MFMA GEMM + bf16 intermediates (378us).
// R10: multi-block scan + 4-stream agg (327us).
// R11: bf16 weights preconverted + conv/fc fused per layer, h in LDS (315us).
// R12: k_layer -> 128 threads / 2 waves, 32 rows x 128 cols per wave:
//      2 A-frags reuse each B-frag -> LDS reads 2.25 -> 1.25 b64 per MFMA.
//      Grid stays 782 blocks (balanced); mapping identical to R8-verified.

#define NEG_SLOPE 0.01f
#define L2EPS 1e-12f

typedef unsigned short u16;
typedef short bf16x8 __attribute__((ext_vector_type(8)));
typedef short s16x4  __attribute__((ext_vector_type(4)));
typedef float f32x4  __attribute__((ext_vector_type(4)));

__device__ __forceinline__ float bf_lo(unsigned int u) {
    union { unsigned int i; float f; } v; v.i = u << 16; return v.f;
}
__device__ __forceinline__ float bf_hi(unsigned int u) {
    union { unsigned int i; float f; } v; v.i = u & 0xffff0000u; return v.f;
}
__device__ __forceinline__ u16 f2bf(float f) {
    union { float f; unsigned int i; } v; v.f = f;
    unsigned int r = v.i + 0x7fffu + ((v.i >> 16) & 1u);
    return (u16)(r >> 16);
}
__device__ __forceinline__ float bf2f(u16 u) {
    union { unsigned int i; float f; } v; v.i = ((unsigned int)u) << 16; return v.f;
}

// ---------------- preprocess: row-normalize x, write bf16 ----------------
__global__ void k_preprocess(const float* __restrict__ x, u16* __restrict__ xp, int N) {
    int node = blockIdx.x * 4 + (threadIdx.x >> 6);
    int lane = threadIdx.x & 63;
    if (node >= N) return;
    float2 v = ((const float2*)x)[(size_t)node * 64 + lane];
    float s = v.x + v.y;
    #pragma unroll
    for (int off = 32; off > 0; off >>= 1) s += __shfl_xor(s, off);
    float rinv = (s == 0.0f) ? 0.0f : 1.0f / s;
    unsigned int lo = f2bf(v.x * rinv), hi = f2bf(v.y * rinv);
    ((unsigned int*)xp)[(size_t)node * 64 + lane] = lo | (hi << 16);
}

// ---------------- weight preconversion: 6 matrices f32 -> bf16 ----------------
// wbf layout: [0]=W1l(16384) [16384]=W1r [32768]=W2l [49152]=W2r
//             [65536]=fc1W(32768) [98304]=fc2W(32768)
__global__ void k_wconv(const float* __restrict__ W1l, const float* __restrict__ W1r,
                        const float* __restrict__ W2l, const float* __restrict__ W2r,
                        const float* __restrict__ f1,  const float* __restrict__ f2,
                        u16* __restrict__ wbf) {
    int i = blockIdx.x * 256 + threadIdx.x;
    if (i >= 32768) return;
    int e = i * 4;
    const float* src; int off;
    if (e < 65536) {
        int m = e >> 14; off = e & 16383;
        src = (m == 0) ? W1l : (m == 1) ? W1r : (m == 2) ? W2l : W2r;
    } else {
        int m = (e - 65536) >> 15; off = (e - 65536) & 32767;
        src = (m == 0) ? f1 : f2;
    }
    float4 v = *(const float4*)(src + off);
    uint2 o;
    o.x = (unsigned int)f2bf(v.x) | ((unsigned int)f2bf(v.y) << 16);
    o.y = (unsigned int)f2bf(v.z) | ((unsigned int)f2bf(v.w) << 16);
    *(uint2*)(wbf + e) = o;
}

// ---------------- CSR build ----------------
__global__ void k_deg(const int* __restrict__ ei, int* __restrict__ deg, int E) {
    int e = blockIdx.x * blockDim.x + threadIdx.x;
    if (e >= E) return;
    atomicAdd(&deg[ei[E + e]], 1);
}

__global__ void k_scan_part(const int* __restrict__ deg, int* __restrict__ rs,
                            int* __restrict__ bsum, int N) {
    __shared__ int wsum[16];
    int t = threadIdx.x;
    int lane = t & 63, w = t >> 6;
    int i = blockIdx.x * 1024 + t;
    int v = (i < N) ? deg[i] : 0;
    int s = v;
    #pragma unroll
    for (int off = 1; off < 64; off <<= 1) {
        int u = __shfl_up(s, off);
        if (lane >= off) s += u;
    }
    if (lane == 63) wsum[w] = s;
    __syncthreads();
    if (w == 0) {
        int x = (lane < 16) ? wsum[lane] : 0;
        #pragma unroll
        for (int off = 1; off < 16; off <<= 1) {
            int u = __shfl_up(x, off);
            if (lane >= off) x += u;
        }
        if (lane < 16) wsum[lane] = x;
    }
    __syncthreads();
    int wexcl = (w == 0) ? 0 : wsum[w - 1];
    if (i < N) rs[i] = wexcl + s - v;
    if (t == 1023) bsum[blockIdx.x] = wexcl + s;
}

__global__ void k_scan_bsum(int* __restrict__ bsum, int* __restrict__ rs,
                            int nb, int N) {
    int lane = threadIdx.x;
    int v = (lane < nb) ? bsum[lane] : 0;
    int s = v;
    #pragma unroll
    for (int off = 1; off < 64; off <<= 1) {
        int u = __shfl_up(s, off);
        if (lane >= off) s += u;
    }
    if (lane < nb) bsum[lane] = s - v;
    if (lane == nb - 1) rs[N] = s;
}

__global__ void k_scan_add(int* __restrict__ rs, int* __restrict__ cursor,
                           const int* __restrict__ bsum, int N) {
    int i = blockIdx.x * 256 + threadIdx.x;
    if (i >= N) return;
    int v = rs[i] + bsum[i >> 10];
    rs[i] = v;
    cursor[i] = v;
}

__global__ void k_fill(const int* __restrict__ ei, int* __restrict__ cursor,
                       int* __restrict__ csr, int E) {
    int e = blockIdx.x * blockDim.x + threadIdx.x;
    if (e >= E) return;
    int src = ei[e];
    int dst = ei[E + e];
    int pos = atomicAdd(&cursor[dst], 1);
    csr[pos] = src;
}

// ---------------- mean aggregation: 4 edge streams x 2-deep, uint4 gathers ----------------
__global__ void k_agg(const u16* __restrict__ feat, const int* __restrict__ csr,
                      const int* __restrict__ rs, u16* __restrict__ mean, int N) {
    int node = blockIdx.x * 4 + (threadIdx.x >> 6);
    int lane = threadIdx.x & 63;
    if (node >= N) return;
    int beg = rs[node], end = rs[node + 1];
    int d = end - beg;
    int q   = lane >> 4;
    int sub = lane & 15;
    const uint4* fp = (const uint4*)feat;
    float4 aA0 = {0.f,0.f,0.f,0.f}, aB0 = {0.f,0.f,0.f,0.f};
    float4 aA1 = {0.f,0.f,0.f,0.f}, aB1 = {0.f,0.f,0.f,0.f};
    int p = beg + q;
    for (; p + 4 < end; p += 8) {
        int s0 = csr[p], s1 = csr[p + 4];
        uint4 v0 = fp[(size_t)s0 * 16 + sub];
        uint4 v1 = fp[(size_t)s1 * 16 + sub];
        aA0.x += bf_lo(v0.x); aA0.y += bf_hi(v0.x);
        aA0.z += bf_lo(v0.y); aA0.w += bf_hi(v0.y);
        aB0.x += bf_lo(v0.z); aB0.y += bf_hi(v0.z);
        aB0.z += bf_lo(v0.w); aB0.w += bf_hi(v0.w);
        aA1.x += bf_lo(v1.x); aA1.y += bf_hi(v1.x);
        aA1.z += bf_lo(v1.y); aA1.w += bf_hi(v1.y);
        aB1.x += bf_lo(v1.z); aB1.y += bf_hi(v1.z);
        aB1.z += bf_lo(v1.w); aB1.w += bf_hi(v1.w);
    }
    if (p < end) {
        int s0 = csr[p];
        uint4 v0 = fp[(size_t)s0 * 16 + sub];
        aA0.x += bf_lo(v0.x); aA0.y += bf_hi(v0.x);
        aA0.z += bf_lo(v0.y); aA0.w += bf_hi(v0.y);
        aB0.x += bf_lo(v0.z); aB0.y += bf_hi(v0.z);
        aB0.z += bf_lo(v0.w); aB0.w += bf_hi(v0.w);
    }
    aA0.x += aA1.x; aA0.y += aA1.y; aA0.z += aA1.z; aA0.w += aA1.w;
    aB0.x += aB1.x; aB0.y += aB1.y; aB0.z += aB1.z; aB0.w += aB1.w;
    #pragma unroll
    for (int off = 16; off <= 32; off <<= 1) {
        aA0.x += __shfl_xor(aA0.x, off); aA0.y += __shfl_xor(aA0.y, off);
        aA0.z += __shfl_xor(aA0.z, off); aA0.w += __shfl_xor(aA0.w, off);
        aB0.x += __shfl_xor(aB0.x, off); aB0.y += __shfl_xor(aB0.y, off);
        aB0.z += __shfl_xor(aB0.z, off); aB0.w += __shfl_xor(aB0.w, off);
    }
    if (q == 0) {
        float inv = (d > 0) ? (1.0f / (float)d) : 0.0f;
        uint4 o;
        o.x = (unsigned int)f2bf(aA0.x * inv) | ((unsigned int)f2bf(aA0.y * inv) << 16);
        o.y = (unsigned int)f2bf(aA0.z * inv) | ((unsigned int)f2bf(aA0.w * inv) << 16);
        o.z = (unsigned int)f2bf(aB0.x * inv) | ((unsigned int)f2bf(aB0.y * inv) << 16);
        o.w = (unsigned int)f2bf(aB0.z * inv) | ((unsigned int)f2bf(aB0.w * inv) << 16);
        ((uint4*)mean)[(size_t)node * 16 + sub] = o;
    }
}

// ---------------- fused layer: h = leaky(l2norm(Am@Wl.T + Ax@Wr.T));
//                  out = leaky([h | Ax] @ Wf.T + b)   (bf16 MFMA)
// BM=64, 128 threads = 2 waves; wave w owns rows w*32..+31, all 128 cols:
// 2 A-frags x 8 B-frags = 16 MFMA per kb, each B-frag read used twice.

#define LOAD_T1(kb_) do {                                                      \
    const u16* As_ = ((kb_) < 4) ? Am : Ax;                                    \
    const u16* Ws_ = ((kb_) < 4) ? Wlb : Wrb;                                  \
    int kl_ = ((kb_) & 3) * 32;                                                \
    int gr_ = i0 + a_row;                                                      \
    if (gr_ < N) {                                                             \
        const u16* ap_ = As_ + (size_t)gr_ * 128 + kl_ + a_half * 16;          \
        sa0 = *(const uint4*)(ap_);  sa1 = *(const uint4*)(ap_ + 8);           \
    } else { sa0 = make_uint4(0u,0u,0u,0u); sa1 = sa0; }                       \
    const u16* wp_ = Ws_ + (size_t)t * 128 + kl_;                              \
    sw0 = *(const uint4*)(wp_);       sw1 = *(const uint4*)(wp_ + 8);          \
    sw2 = *(const uint4*)(wp_ + 16);  sw3 = *(const uint4*)(wp_ + 24);         \
} while (0)

#define LOAD_T2(kb_) do {                                                      \
    int kl_ = ((kb_) & 3) * 32;                                                \
    if ((kb_) >= 4) {                                                          \
        int gr_ = i0 + a_row;                                                  \
        if (gr_ < N) {                                                         \
            const u16* ap_ = Ax + (size_t)gr_ * 128 + kl_ + a_half * 16;       \
            sa0 = *(const uint4*)(ap_);  sa1 = *(const uint4*)(ap_ + 8);       \
        } else { sa0 = make_uint4(0u,0u,0u,0u); sa1 = sa0; }                   \
    }                                                                          \
    int ko_ = kl_ + (((kb_) >= 4) ? 128 : 0);                                  \
    const u16* wp_ = Wfb + (size_t)t * 256 + ko_;                              \
    sw0 = *(const uint4*)(wp_);       sw1 = *(const uint4*)(wp_ + 8);          \
    sw2 = *(const uint4*)(wp_ + 16);  sw3 = *(const uint4*)(wp_ + 24);         \
} while (0)

#define STORE_A() do {                                                         \
    *(uint4*)&Al[a_half][a_row][0] = sa0;                                      \
    *(uint4*)&Al[a_half][a_row][8] = sa1;                                      \
} while (0)
#define STORE_W() do {                                                         \
    *(uint4*)&Wl[0][t][0] = sw0;  *(uint4*)&Wl[0][t][8] = sw1;                 \
    *(uint4*)&Wl[1][t][0] = sw2;  *(uint4*)&Wl[1][t][8] = sw3;                 \
} while (0)

__global__ __launch_bounds__(128) void k_layer(
    const u16* __restrict__ Am, const u16* __restrict__ Ax,
    const u16* __restrict__ Wlb, const u16* __restrict__ Wrb,
    const u16* __restrict__ Wfb, const float* __restrict__ bias,
    u16* __restrict__ out, int N)
{
    __shared__ u16 Al[2][64][40];    // A staging: [k-half][row][16+pad]
    __shared__ u16 Wl[2][128][40];   // W staging
    __shared__ u16 hT[64][136];      // h tile (272 B stride)
    int t = threadIdx.x;             // 0..127
    int i0 = blockIdx.x * 64;

    // staging map: A row t>>1 (half t&1); W full row t (both halves)
    int a_row  = t >> 1;
    int a_half = t & 1;

    // compute map: wave wid owns rows wid*32..+31
    int c16 = t & 15;
    int g   = (t >> 4) & 3;
    int wid = t >> 6;                // 0..1
    int ar0 = wid * 32 + c16;
    int ar1 = ar0 + 16;
    int g4  = g * 4;

    f32x4 acc0[8], acc1[8];
    #pragma unroll
    for (int cb = 0; cb < 8; ++cb) {
        acc0[cb] = (f32x4){0.f, 0.f, 0.f, 0.f};
        acc1[cb] = (f32x4){0.f, 0.f, 0.f, 0.f};
    }

    uint4 sa0, sa1, sw0, sw1, sw2, sw3;
    union U8 { bf16x8 v; s16x4 h[2]; };

    // ---- phase 1: conv GEMM ----
    LOAD_T1(0);
    for (int kb = 0; kb < 8; ++kb) {
        __syncthreads();
        STORE_A(); STORE_W();
        __syncthreads();
        if (kb < 7) LOAD_T1(kb + 1);

        U8 af0, af1;
        af0.h[0] = *(const s16x4*)&Al[0][ar0][g4];
        af0.h[1] = *(const s16x4*)&Al[1][ar0][g4];
        af1.h[0] = *(const s16x4*)&Al[0][ar1][g4];
        af1.h[1] = *(const s16x4*)&Al[1][ar1][g4];
        #pragma unroll
        for (int cb = 0; cb < 8; ++cb) {
            U8 bfr;
            int wr = cb * 16 + c16;
            bfr.h[0] = *(const s16x4*)&Wl[0][wr][g4];
            bfr.h[1] = *(const s16x4*)&Wl[1][wr][g4];
            acc0[cb] = __builtin_amdgcn_mfma_f32_16x16x32_bf16(af0.v, bfr.v, acc0[cb], 0, 0, 0);
            acc1[cb] = __builtin_amdgcn_mfma_f32_16x16x32_bf16(af1.v, bfr.v, acc1[cb], 0, 0, 0);
        }
    }

    // ---- epilogue 1: l2norm + leaky -> hT (LDS) ----
    {
        float s0 = 0.f, s1 = 0.f, s2 = 0.f, s3 = 0.f;
        float u0 = 0.f, u1 = 0.f, u2 = 0.f, u3 = 0.f;
        #pragma unroll
        for (int cb = 0; cb < 8; ++cb) {
            s0 += acc0[cb][0] * acc0[cb][0];
            s1 += acc0[cb][1] * acc0[cb][1];
            s2 += acc0[cb][2] * acc0[cb][2];
            s3 += acc0[cb][3] * acc0[cb][3];
            u0 += acc1[cb][0] * acc1[cb][0];
            u1 += acc1[cb][1] * acc1[cb][1];
            u2 += acc1[cb][2] * acc1[cb][2];
            u3 += acc1[cb][3] * acc1[cb][3];
        }
        #pragma unroll
        for (int off = 1; off < 16; off <<= 1) {
            s0 += __shfl_xor(s0, off); s1 += __shfl_xor(s1, off);
            s2 += __shfl_xor(s2, off); s3 += __shfl_xor(s3, off);
            u0 += __shfl_xor(u0, off); u1 += __shfl_xor(u1, off);
            u2 += __shfl_xor(u2, off); u3 += __shfl_xor(u3, off);
        }
        float scs0[4], scs1[4];
        scs0[0] = 1.0f / fmaxf(sqrtf(s0), L2EPS);
        scs0[1] = 1.0f / fmaxf(sqrtf(s1), L2EPS);
        scs0[2] = 1.0f / fmaxf(sqrtf(s2), L2EPS);
        scs0[3] = 1.0f / fmaxf(sqrtf(s3), L2EPS);
        scs1[0] = 1.0f / fmaxf(sqrtf(u0), L2EPS);
        scs1[1] = 1.0f / fmaxf(sqrtf(u1), L2EPS);
        scs1[2] = 1.0f / fmaxf(sqrtf(u2), L2EPS);
        scs1[3] = 1.0f / fmaxf(sqrtf(u3), L2EPS);
        #pragma unroll
        for (int reg = 0; reg < 4; ++reg) {
            int rl0 = wid * 32 + g * 4 + reg;
            #pragma unroll
            for (int cb = 0; cb < 8; ++cb) {
                float xv = acc0[cb][reg] * scs0[reg];
                float r = (xv >= 0.f) ? xv : NEG_SLOPE * xv;
                hT[rl0][cb * 16 + c16] = f2bf(r);
                float yv = acc1[cb][reg] * scs1[reg];
                float q = (yv >= 0.f) ? yv : NEG_SLOPE * yv;
                hT[rl0 + 16][cb * 16 + c16] = f2bf(q);
            }
        }
    }

    // reset accumulators for phase 2
    #pragma unroll
    for (int cb = 0; cb < 8; ++cb) {
        acc0[cb] = (f32x4){0.f, 0.f, 0.f, 0.f};
        acc1[cb] = (f32x4){0.f, 0.f, 0.f, 0.f};
    }

    // ---- phase 2: fc GEMM ([h | Ax] @ Wf.T) ----
    LOAD_T2(0);
    for (int kb = 0; kb < 8; ++kb) {
        __syncthreads();   // kb==0: also orders hT writes before reads below
        if (kb >= 4) STORE_A();
        STORE_W();
        __syncthreads();
        if (kb < 7) LOAD_T2(kb + 1);

        U8 af0, af1;
        if (kb < 4) {
            af0.h[0] = *(const s16x4*)&hT[ar0][kb * 32 + g4];
            af0.h[1] = *(const s16x4*)&hT[ar0][kb * 32 + 16 + g4];
            af1.h[0] = *(const s16x4*)&hT[ar1][kb * 32 + g4];
            af1.h[1] = *(const s16x4*)&hT[ar1][kb * 32 + 16 + g4];
        } else {
            af0.h[0] = *(const s16x4*)&Al[0][ar0][g4];
            af0.h[1] = *(const s16x4*)&Al[1][ar0][g4];
            af1.h[0] = *(const s16x4*)&Al[0][ar1][g4];
            af1.h[1] = *(const s16x4*)&Al[1][ar1][g4];
        }
        #pragma unroll
        for (int cb = 0; cb < 8; ++cb) {
            U8 bfr;
            int wr = cb * 16 + c16;
            bfr.h[0] = *(const s16x4*)&Wl[0][wr][g4];
            bfr.h[1] = *(const s16x4*)&Wl[1][wr][g4];
            acc0[cb] = __builtin_amdgcn_mfma_f32_16x16x32_bf16(af0.v, bfr.v, acc0[cb], 0, 0, 0);
            acc1[cb] = __builtin_amdgcn_mfma_f32_16x16x32_bf16(af1.v, bfr.v, acc1[cb], 0, 0, 0);
        }
    }

    // ---- epilogue 2: bias + leaky -> out (bf16, global) ----
    float bv[8];
    #pragma unroll
    for (int cb = 0; cb < 8; ++cb) bv[cb] = bias[cb * 16 + c16];
    int rbase = i0 + wid * 32 + g * 4;
    #pragma unroll
    for (int reg = 0; reg < 4; ++reg) {
        int gr0 = rbase + reg;
        if (gr0 < N) {
            #pragma unroll
            for (int cb = 0; cb < 8; ++cb) {
                float xv = acc0[cb][reg] + bv[cb];
                float r = (xv >= 0.f) ? xv : NEG_SLOPE * xv;
                out[(size_t)gr0 * 128 + cb * 16 + c16] = f2bf(r);
            }
        }
        int gr1 = rbase + 16 + reg;
        if (gr1 < N) {
            #pragma unroll
            for (int cb = 0; cb < 8; ++cb) {
                float yv = acc1[cb][reg] + bv[cb];
                float q = (yv >= 0.f) ? yv : NEG_SLOPE * yv;
                out[(size_t)gr1 * 128 + cb * 16 + c16] = f2bf(q);
            }
        }
    }
}

// ---------------- pool: chunked partial sums over sorted batch (bf16 in) ----------------
#define POOL_ROWS 128
__global__ void k_pool(const u16* __restrict__ h3, const int* __restrict__ batch,
                       float* __restrict__ pooled, int N) {
    int f = threadIdx.x;
    int base = blockIdx.x * POOL_ROWS;
    if (base >= N) return;
    int end = min(base + POOL_ROWS, N);
    float acc = 0.f;
    int cur = batch[base];
    for (int i = base; i < end; ++i) {
        int g = batch[i];
        if (g != cur) {
            atomicAdd(&pooled[cur * 128 + f], acc);
            acc = 0.f; cur = g;
        }
        acc += bf2f(h3[(size_t)i * 128 + f]);
    }
    atomicAdd(&pooled[cur * 128 + f], acc);
}

__global__ void k_fc3(const float* __restrict__ pooled, const float* __restrict__ W,
                      const float* __restrict__ b, float* __restrict__ out) {
    int g = blockIdx.x, f = threadIdx.x;
    __shared__ float prow[128];
    __shared__ float red[128];
    prow[f] = pooled[g * 128 + f];
    __syncthreads();
    float acc = b[f];
    #pragma unroll 8
    for (int k = 0; k < 128; ++k) acc += prow[k] * W[f * 128 + k];
    float v = (acc >= 0.f) ? acc : NEG_SLOPE * acc;
    red[f] = v * v;
    __syncthreads();
    for (int o = 64; o > 0; o >>= 1) {
        if (f < o) red[f] += red[f + o];
        __syncthreads();
    }
    float sc = 1.0f / fmaxf(sqrtf(red[0]), L2EPS);
    out[g * 128 + f] = v * sc;
}

// ---------------- launch ----------------
extern "C" void kernel_launch(void* const* d_in, const int* in_sizes, int n_in,
                              void* d_out, int out_size, void* d_ws, size_t ws_size,
                              hipStream_t stream) {
    const float* x    = (const float*)d_in[0];
    const int*   ei   = (const int*)d_in[1];
    const int*   batch= (const int*)d_in[2];
    const float* W1l  = (const float*)d_in[3];
    const float* W1r  = (const float*)d_in[4];
    const float* W2l  = (const float*)d_in[5];
    const float* W2r  = (const float*)d_in[6];
    const float* fc1W = (const float*)d_in[7];
    const float* fc1b = (const float*)d_in[8];
    const float* fc2W = (const float*)d_in[9];
    const float* fc2b = (const float*)d_in[10];
    const float* fc3W = (const float*)d_in[11];
    const float* fc3b = (const float*)d_in[12];

    int N = in_sizes[0] / 128;
    int E = in_sizes[1] / 2;
    int G = out_size / 128;
    float* out = (float*)d_out;

    char* ws = (char*)d_ws;
    size_t off = 0;
    auto alloc = [&](size_t bytes) -> void* {
        void* p = ws + off;
        off = (off + bytes + 255) & ~(size_t)255;
        return p;
    };
    u16* xp     = (u16*)alloc((size_t)N * 128 * 2);  // x_pre, later reused as h3
    u16* mean   = (u16*)alloc((size_t)N * 128 * 2);
    u16* h1     = (u16*)alloc((size_t)N * 128 * 2);
    u16* wbf    = (u16*)alloc(131072 * 2);           // all weights, bf16
    float* pooled = (float*)alloc((size_t)G * 128 * 4);
    int* deg    = (int*)alloc((size_t)N * 4);
    int* rs     = (int*)alloc((size_t)(N + 1) * 4);
    int* cursor = (int*)alloc((size_t)N * 4);
    int* csr    = (int*)alloc((size_t)E * 4);
    int* bsum   = (int*)alloc(64 * 4);
    (void)ws_size; (void)n_in;

    hipMemsetAsync(deg, 0, (size_t)N * 4, stream);
    hipMemsetAsync(pooled, 0, (size_t)G * 128 * 4, stream);

    int nb = (N + 1023) / 1024;
    k_preprocess<<<(N + 3) / 4, 256, 0, stream>>>(x, xp, N);
    k_wconv<<<128, 256, 0, stream>>>(W1l, W1r, W2l, W2r, fc1W, fc2W, wbf);
    k_deg<<<(E + 255) / 256, 256, 0, stream>>>(ei, deg, E);
    k_scan_part<<<nb, 1024, 0, stream>>>(deg, rs, bsum, N);
    k_scan_bsum<<<1, 64, 0, stream>>>(bsum, rs, nb, N);
    k_scan_add<<<(N + 255) / 256, 256, 0, stream>>>(rs, cursor, bsum, N);
    k_fill<<<(E + 255) / 256, 256, 0, stream>>>(ei, cursor, csr, E);

    int gb = (N + 63) / 64;
    // layer 1: agg(xp) -> h -> h1 (fused conv1+fc1)
    k_agg<<<(N + 3) / 4, 256, 0, stream>>>(xp, csr, rs, mean, N);
    k_layer<<<gb, 128, 0, stream>>>(
        mean, xp, wbf, wbf + 16384, wbf + 65536, fc1b, h1, N);

    // layer 2: agg(h1) -> h2 -> h3 (fused conv2+fc2); h3 -> xp buffer
    k_agg<<<(N + 3) / 4, 256, 0, stream>>>(h1, csr, rs, mean, N);
    k_layer<<<gb, 128, 0, stream>>>(
        mean, h1, wbf + 32768, wbf + 49152, wbf + 98304, fc2b, xp, N);

    // pool + head
    k_pool<<<(N + POOL_ROWS - 1) / POOL_ROWS, 128, 0, stream>>>(xp, batch, pooled, N);
    k_fc3<<<G, 128, 0, stream>>>(pooled, fc3W, fc3b, out);
}